// Round 6
// baseline (442.982 us; speedup 1.0000x reference)
//
#include <hip/hip_runtime.h>
#include <cstdint>

typedef short short8 __attribute__((ext_vector_type(8)));
typedef float f32x4  __attribute__((ext_vector_type(4)));

// RNE float -> bf16 hi + bf16 lo split (scalar)
__device__ __forceinline__ void split2(float x, short& h, short& l) {
  unsigned u  = __float_as_uint(x);
  unsigned rh = u + 0x7FFFu + ((u >> 16) & 1u);
  h = (short)(rh >> 16);
  float hf = __uint_as_float((rh >> 16) << 16);
  float lf = x - hf;
  unsigned ul = __float_as_uint(lf);
  unsigned rl = ul + 0x7FFFu + ((ul >> 16) & 1u);
  l = (short)(rl >> 16);
}

// float4 -> packed bf16 hi pair + lo pair (v_cvt_pk_bf16_f32)
__device__ __forceinline__ void split4(float4 a, uint2& hp, uint2& lp) {
  unsigned hp0, hp1, lp0, lp1;
  asm("v_cvt_pk_bf16_f32 %0, %1, %2" : "=v"(hp0) : "v"(a.x), "v"(a.y));
  asm("v_cvt_pk_bf16_f32 %0, %1, %2" : "=v"(hp1) : "v"(a.z), "v"(a.w));
  float h0 = __uint_as_float(hp0 << 16);
  float h1 = __uint_as_float(hp0 & 0xFFFF0000u);
  float h2 = __uint_as_float(hp1 << 16);
  float h3 = __uint_as_float(hp1 & 0xFFFF0000u);
  float l0 = a.x - h0, l1 = a.y - h1, l2 = a.z - h2, l3 = a.w - h3;
  asm("v_cvt_pk_bf16_f32 %0, %1, %2" : "=v"(lp0) : "v"(l0), "v"(l1));
  asm("v_cvt_pk_bf16_f32 %0, %1, %2" : "=v"(lp1) : "v"(l2), "v"(l3));
  hp = make_uint2(hp0, hp1);
  lp = make_uint2(lp0, lp1);
}

// async global->LDS, 16B per lane, LDS dest = base + lane*16 (linear)
__device__ __forceinline__ void gl_lds16(const void* g, void* l) {
  __builtin_amdgcn_global_load_lds(
      (const __attribute__((address_space(1))) unsigned int*)g,
      (__attribute__((address_space(3))) unsigned int*)l, 16, 0, 0);
}

// ---------------------------------------------------------------------------
__global__ __launch_bounds__(256) void init_head(int* __restrict__ head, int N)
{
  const int i = blockIdx.x * 256 + threadIdx.x;
  if (i < N) head[i] = -1;
}

// ---------------------------------------------------------------------------
// Pre-convert all weight matrices [K][64] f32 -> bf16 hi/lo in MFMA B-frag
// order. k-row segments (padded to mult of 32):
//   Wi:0(512) Wt:512(768) Wn:1280(K=16) Wc:1312(K=8) Wf:1344(256)
//   Wm1A:1600(64) Wm1B:1664(64)   total 1728 k-rows -> steps 0..53
// ---------------------------------------------------------------------------
__global__ __launch_bounds__(256) void prep_w(
    const float* __restrict__ Wi, const float* __restrict__ Wt,
    const float* __restrict__ Wn, const float* __restrict__ Wc,
    const float* __restrict__ Wf, const float* __restrict__ Wm1,
    short* __restrict__ hi, short* __restrict__ lo)
{
  int idx = blockIdx.x * 256 + threadIdx.x;
  if (idx >= 1728 * 64) return;
  int kp = idx >> 6, col = idx & 63;
  const float* W; int K, kloc, base;
  if (kp < 512)       { W = Wi;            K = 512; kloc = kp;        base = 0;    }
  else if (kp < 1280) { W = Wt;            K = 768; kloc = kp - 512;  base = 512;  }
  else if (kp < 1312) { W = Wn;            K = 16;  kloc = kp - 1280; base = 1280; }
  else if (kp < 1344) { W = Wc;            K = 8;   kloc = kp - 1312; base = 1312; }
  else if (kp < 1600) { W = Wf;            K = 256; kloc = kp - 1344; base = 1344; }
  else if (kp < 1664) { W = Wm1;           K = 64;  kloc = kp - 1600; base = 1600; }
  else                { W = Wm1 + 64 * 64; K = 64;  kloc = kp - 1664; base = 1664; }
  float x = (kloc < K) ? W[(size_t)kloc * 64 + col] : 0.f;
  short h, l; split2(x, h, l);
  int s = kloc >> 5;
  int addr = ((s * 4 + (col >> 4)) * 64 + ((col & 15) | (((kloc >> 3) & 3) << 4))) * 8 + (kloc & 7);
  size_t o = (size_t)base * 64 + addr;
  hi[o] = h; lo[o] = l;
}

// ---------------------------------------------------------------------------
// Fused encoder v2: counted-vmcnt global_load_lds pipeline.
// 64-row tiles, 4 waves. 42 K-steps (image 16, tweets 24, nump 1, catg 1).
// LDS (80KB): A ring 4x8KB f32 (XOR-swizzled content), W ring 4x8KB bf16
// frags (hi|lo), hfrag 2x(2048+2048) shorts for the stage-2 A-fragments.
// Steady loop: stage(t+2) -> s_waitcnt vmcnt(8) -> s_barrier -> cvt+MFMA.
// ---------------------------------------------------------------------------
#define ENC_STEPS 42
#define A_OFF   0
#define W_OFF   32768
#define HHI_OFF 65536
#define HLO_OFF 73728

__global__ __launch_bounds__(256) void encoder(
    const float* __restrict__ image, const float* __restrict__ tweets,
    const float* __restrict__ nump, const float* __restrict__ catg,
    const short* __restrict__ Whi, const short* __restrict__ Wlo,
    const float* __restrict__ bi, const float* __restrict__ bt,
    const float* __restrict__ bn, const float* __restrict__ bc,
    const float* __restrict__ bf, float* __restrict__ nf, int M)
{
  __shared__ uint4 smem4[81920 / 16];
  char* lds = (char*)smem4;

  const int tid  = threadIdx.x;
  const int m0   = blockIdx.x * 64;
  const int w    = tid >> 6, l = tid & 63;

  f32x4 acc[4], acc2[4];
#pragma unroll
  for (int n = 0; n < 4; n++) {
    acc[n]  = (f32x4){0.f, 0.f, 0.f, 0.f};
    acc2[n] = (f32x4){0.f, 0.f, 0.f, 0.f};
  }

  // issue the 4 (2 A + 2 W) gload_lds for step tt into ring slot b
  auto stage = [&](int tt, int b) {
    const float* As; int lda, kbase, kmax;
    if (tt < 16)      { As = image;  lda = 512; kbase = tt * 32;        kmax = 7; }
    else if (tt < 40) { As = tweets; lda = 768; kbase = (tt - 16) * 32; kmax = 7; }
    else if (tt == 40){ As = nump;   lda = 16;  kbase = 0;              kmax = 3; }
    else              { As = catg;   lda = 8;   kbase = 0;              kmax = 1; }
#pragma unroll
    for (int jj = 0; jj < 2; jj++) {
      const int j = w * 2 + jj;
      // A chunk j: lane i -> row j*8+(i>>3), swizzled col chunk (i&7)^(i>>3)
      {
        int row  = j * 8 + (l >> 3);
        int grow = m0 + row; if (grow >= M) grow = 0;
        int cc   = (l & 7) ^ (l >> 3);
        int k    = (cc <= kmax) ? (kbase + cc * 4) : kbase;  // clamp: W rows are 0 there
        gl_lds16(As + (size_t)grow * lda + k, lds + A_OFF + b * 8192 + j * 1024);
      }
      // W chunk j: j<4 -> hi n-tile j ; j>=4 -> lo n-tile j-4  (linear copy)
      {
        const short* gW = (j < 4) ? (Whi + (size_t)tt * 2048 + j * 512)
                                  : (Wlo + (size_t)tt * 2048 + (j - 4) * 512);
        gl_lds16(gW + l * 8, lds + W_OFF + b * 8192 + j * 1024);
      }
    }
  };

  // stage-2: split-write h into hfrag, then MFMA vs Wf k-block of this segment
  auto seg2_phase = [&](int seg, const float* bias) {
    short* hh = (short*)(lds + HHI_OFF);
    short* hl = (short*)(lds + HLO_OFF);
#pragma unroll
    for (int n = 0; n < 4; n++) {
      const int k = n * 16 + (l & 15);
#pragma unroll
      for (int j = 0; j < 4; j++) {
        const int row = w * 16 + (l >> 4) * 4 + j;
        float h = fmaxf(acc[n][j] + bias[k], 0.f);
        short vh, vl; split2(h, vh, vl);
        const int addr = (k >> 5) * 2048 + (row >> 4) * 512 +
                         ((row & 15) | (((k >> 3) & 3) << 4)) * 8 + (k & 7);
        hh[addr] = vh; hl[addr] = vl;
      }
      acc[n] = (f32x4){0.f, 0.f, 0.f, 0.f};
    }
    __syncthreads();
#pragma unroll
    for (int ks2 = 0; ks2 < 2; ks2++) {
      short8 ahi = *reinterpret_cast<const short8*>(&hh[ks2 * 2048 + w * 512 + l * 8]);
      short8 alo = *reinterpret_cast<const short8*>(&hl[ks2 * 2048 + w * 512 + l * 8]);
      const int st = 42 + seg * 2 + ks2;
#pragma unroll
      for (int n = 0; n < 4; n++) {
        short8 whi = *reinterpret_cast<const short8*>(&Whi[((size_t)st * 4 + n) * 512 + l * 8]);
        short8 wlo = *reinterpret_cast<const short8*>(&Wlo[((size_t)st * 4 + n) * 512 + l * 8]);
        acc2[n] = __builtin_amdgcn_mfma_f32_16x16x32_bf16(ahi, whi, acc2[n], 0, 0, 0);
        acc2[n] = __builtin_amdgcn_mfma_f32_16x16x32_bf16(alo, whi, acc2[n], 0, 0, 0);
        acc2[n] = __builtin_amdgcn_mfma_f32_16x16x32_bf16(ahi, wlo, acc2[n], 0, 0, 0);
      }
    }
    __syncthreads();
  };

  // prologue: 2 stages in flight
  stage(0, 0);
  stage(1, 1);

  for (int t = 0; t < ENC_STEPS; t++) {
    if (t + 2 < ENC_STEPS) stage(t + 2, (t + 2) & 3);
    if (t <= ENC_STEPS - 3)      asm volatile("s_waitcnt vmcnt(8)" ::: "memory");
    else if (t == ENC_STEPS - 2) asm volatile("s_waitcnt vmcnt(4)" ::: "memory");
    else                         asm volatile("s_waitcnt vmcnt(0)" ::: "memory");
    __builtin_amdgcn_sched_barrier(0);
    __builtin_amdgcn_s_barrier();
    __builtin_amdgcn_sched_barrier(0);

    const int b = t & 3;
    const char* Ab = lds + A_OFF + b * 8192;
    const char* Wb = lds + W_OFF + b * 8192;
    // A frag: row = w*16+(l&15); chunks (l>>4)*2, +1; XOR bank swizzle (row&7)=l&7
    const int row = w * 16 + (l & 15);
    float4 a0 = *reinterpret_cast<const float4*>(
        Ab + row * 128 + ((((l >> 4) * 2 + 0) ^ (l & 7)) * 16));
    float4 a1 = *reinterpret_cast<const float4*>(
        Ab + row * 128 + ((((l >> 4) * 2 + 1) ^ (l & 7)) * 16));
    uint2 h01, l01, h23, l23;
    split4(a0, h01, l01);
    split4(a1, h23, l23);
    uint4 ahi_u = make_uint4(h01.x, h01.y, h23.x, h23.y);
    uint4 alo_u = make_uint4(l01.x, l01.y, l23.x, l23.y);
    short8 ahi = *reinterpret_cast<short8*>(&ahi_u);
    short8 alo = *reinterpret_cast<short8*>(&alo_u);
#pragma unroll
    for (int n = 0; n < 4; n++) {
      short8 whi = *reinterpret_cast<const short8*>(Wb + n * 1024 + l * 16);
      short8 wlo = *reinterpret_cast<const short8*>(Wb + 4096 + n * 1024 + l * 16);
      acc[n] = __builtin_amdgcn_mfma_f32_16x16x32_bf16(ahi, whi, acc[n], 0, 0, 0);
      acc[n] = __builtin_amdgcn_mfma_f32_16x16x32_bf16(alo, whi, acc[n], 0, 0, 0);
      acc[n] = __builtin_amdgcn_mfma_f32_16x16x32_bf16(ahi, wlo, acc[n], 0, 0, 0);
    }

    if (t == 15)      seg2_phase(0, bi);
    else if (t == 39) seg2_phase(1, bt);
    else if (t == 40) seg2_phase(2, bn);
    else if (t == 41) seg2_phase(3, bc);
  }

  // epilogue: nf = relu(acc2 + bf)
  const int rb  = m0 + w * 16 + (l >> 4) * 4;
  const int c15 = l & 15;
#pragma unroll
  for (int n = 0; n < 4; n++) {
    const int c = n * 16 + c15;
    const float bb = bf[c];
#pragma unroll
    for (int j = 0; j < 4; j++) {
      const int r = rb + j;
      if (r < M) nf[(size_t)r * 64 + c] = fmaxf(acc2[n][j] + bb, 0.f);
    }
  }
}

// ---------------------------------------------------------------------------
// Edge tables via MFMA. blocks [0,gT): Atab   blocks [gT,2gT): Btab
// ---------------------------------------------------------------------------
__global__ __launch_bounds__(256) void table_kernel(
    const float* __restrict__ nf, const float* __restrict__ Eet,
    const short* __restrict__ Whi, const short* __restrict__ Wlo,
    const float* __restrict__ bm1,
    float* __restrict__ Atab, float* __restrict__ Btab, int N3, int gT)
{
  const bool isB    = (int)blockIdx.x >= gT;
  const int  m0     = (isB ? (int)blockIdx.x - gT : (int)blockIdx.x) * 64;
  const int  eoff   = isB ? 64 : 0;
  const int  wstep0 = isB ? 52 : 50;
  float*     Tab    = isB ? Btab : Atab;

  __shared__ short Ahi[2][2048];
  __shared__ short Alo[2][2048];
  const int tid  = threadIdx.x;
  const int w    = tid >> 6, l = tid & 63;
  const int srow = tid >> 3;
  const int k0   = (tid & 7) * 4;
  const int i0   = k0 & 7;
  const int kg   = k0 >> 3;

#pragma unroll
  for (int ks2 = 0; ks2 < 2; ks2++) {
#pragma unroll
    for (int r2 = 0; r2 < 2; r2++) {
      const int row = srow + r2 * 32;
      const int rg  = m0 + row;
      float4 v = make_float4(0.f, 0.f, 0.f, 0.f);
      if (rg < N3) {
        const int n = rg / 3;
        const int t = rg - n * 3;
        const int k = ks2 * 32 + k0;
        float4 x = *reinterpret_cast<const float4*>(&nf[(size_t)n * 64 + k]);
        float4 e = *reinterpret_cast<const float4*>(&Eet[(size_t)t * 128 + eoff + k]);
        v.x = fmaxf(x.x + e.x, 0.f); v.y = fmaxf(x.y + e.y, 0.f);
        v.z = fmaxf(x.z + e.z, 0.f); v.w = fmaxf(x.w + e.w, 0.f);
      }
      uint2 hp, lp; split4(v, hp, lp);
      const int addr = (row >> 4) * 512 + (((row & 15) | (kg << 4)) * 8 + i0);
      *reinterpret_cast<uint2*>(&Ahi[ks2][addr]) = hp;
      *reinterpret_cast<uint2*>(&Alo[ks2][addr]) = lp;
    }
  }
  __syncthreads();

  f32x4 acc[4];
#pragma unroll
  for (int n = 0; n < 4; n++) acc[n] = (f32x4){0.f, 0.f, 0.f, 0.f};

#pragma unroll
  for (int ks2 = 0; ks2 < 2; ks2++) {
    short8 ahi = *reinterpret_cast<const short8*>(&Ahi[ks2][w * 512 + l * 8]);
    short8 alo = *reinterpret_cast<const short8*>(&Alo[ks2][w * 512 + l * 8]);
#pragma unroll
    for (int n = 0; n < 4; n++) {
      short8 whi = *reinterpret_cast<const short8*>(&Whi[((size_t)(wstep0 + ks2) * 4 + n) * 512 + l * 8]);
      short8 wlo = *reinterpret_cast<const short8*>(&Wlo[((size_t)(wstep0 + ks2) * 4 + n) * 512 + l * 8]);
      acc[n] = __builtin_amdgcn_mfma_f32_16x16x32_bf16(ahi, whi, acc[n], 0, 0, 0);
      acc[n] = __builtin_amdgcn_mfma_f32_16x16x32_bf16(alo, whi, acc[n], 0, 0, 0);
      acc[n] = __builtin_amdgcn_mfma_f32_16x16x32_bf16(ahi, wlo, acc[n], 0, 0, 0);
    }
  }

  const int rb  = m0 + w * 16 + (l >> 4) * 4;
  const int c15 = l & 15;
#pragma unroll
  for (int n = 0; n < 4; n++) {
    const int c = n * 16 + c15;
    const float bb = isB ? 0.f : bm1[c];
#pragma unroll
    for (int j = 0; j < 4; j++) {
      const int r = rb + j;
      if (r < N3) Tab[(size_t)r * 64 + c] = acc[n][j] + bb;
    }
  }
}

// ---------------------------------------------------------------------------
// 16 lanes per edge: logits -> sigmoid -> Bernoulli(u) -> linked list append
// ---------------------------------------------------------------------------
__global__ __launch_bounds__(256) void edge_kernel(
    const int* __restrict__ ei, const int* __restrict__ et,
    const float* __restrict__ u,
    const float* __restrict__ Atab, const float* __restrict__ Btab,
    const float* __restrict__ Wm2, const float* __restrict__ bm2,
    int* __restrict__ head, int* __restrict__ nxt, int E)
{
  const int tid = threadIdx.x;
  const int e   = blockIdx.x * 16 + (tid >> 4);
  const int sub = tid & 15;
  if (e >= E) return;

  const int sn = ei[e];
  const int dn = ei[E + e];
  const int t  = et[e];

  float4 a  = *reinterpret_cast<const float4*>(Atab + ((size_t)sn * 3 + t) * 64 + sub * 4);
  float4 b  = *reinterpret_cast<const float4*>(Btab + ((size_t)dn * 3 + t) * 64 + sub * 4);
  float4 wv = *reinterpret_cast<const float4*>(Wm2 + sub * 4);

  float v = fmaxf(a.x + b.x, 0.f) * wv.x;
  v = fmaf(fmaxf(a.y + b.y, 0.f), wv.y, v);
  v = fmaf(fmaxf(a.z + b.z, 0.f), wv.z, v);
  v = fmaf(fmaxf(a.w + b.w, 0.f), wv.w, v);
  v += __shfl_xor(v, 1);
  v += __shfl_xor(v, 2);
  v += __shfl_xor(v, 4);
  v += __shfl_xor(v, 8);

  if (sub == 0) {
    const float p = 1.f / (1.f + expf(-(v + bm2[0])));
    if (u[e] < p) {
      nxt[e] = atomicExch(&head[sn], e);
    }
  }
}

// ---------------------------------------------------------------------------
// one wave per node: walk chain, accumulate nf[dst] in double, out = agg@Wcls
// ---------------------------------------------------------------------------
__global__ __launch_bounds__(256) void node_kernel(
    const int* __restrict__ head, const int* __restrict__ nxt,
    const int* __restrict__ ei,
    const float* __restrict__ nf,
    const float* __restrict__ Wcls, const float* __restrict__ bcls,
    float* __restrict__ out, int N, int E)
{
  const int n    = (int)((blockIdx.x * (unsigned)blockDim.x + threadIdx.x) >> 6);
  const int lane = threadIdx.x & 63;
  if (n >= N) return;

  double acc = 0.0;
  int    c   = 0;
  int    e   = head[n];
  while (e >= 0) {
    const int dn = ei[E + e];
    acc += (double)nf[(size_t)dn * 64 + lane];
    c++;
    e = nxt[e];
  }

  const float agg = (c > 0) ? (float)(acc / (double)c) : nf[(size_t)n * 64 + lane];
  float r0 = agg * Wcls[lane * 2 + 0];
  float r1 = agg * Wcls[lane * 2 + 1];
#pragma unroll
  for (int off = 32; off; off >>= 1) {
    r0 += __shfl_xor(r0, off, 64);
    r1 += __shfl_xor(r1, off, 64);
  }
  if (lane == 0) {
    out[(size_t)n * 2 + 0] = r0 + bcls[0];
    out[(size_t)n * 2 + 1] = r1 + bcls[1];
  }
}

// ---------------------------------------------------------------------------
extern "C" void kernel_launch(void* const* d_in, const int* in_sizes, int n_in,
                              void* d_out, int out_size, void* d_ws, size_t ws_size,
                              hipStream_t stream)
{
  const float* image    = (const float*)d_in[0];
  const float* tweets   = (const float*)d_in[1];
  const float* num_prop = (const float*)d_in[2];
  const float* category = (const float*)d_in[3];
  const int*   ei       = (const int*)  d_in[4];
  const int*   et       = (const int*)  d_in[5];
  // d_in[6] = eps : unused (z is dead code)
  const float* u        = (const float*)d_in[7];
  const float* Wi  = (const float*)d_in[8],  *bi  = (const float*)d_in[9];
  const float* Wt  = (const float*)d_in[10], *bt  = (const float*)d_in[11];
  const float* Wn  = (const float*)d_in[12], *bn  = (const float*)d_in[13];
  const float* Wc  = (const float*)d_in[14], *bc  = (const float*)d_in[15];
  const float* Wf  = (const float*)d_in[16], *bf  = (const float*)d_in[17];
  const float* Eet = (const float*)d_in[18];
  // d_in[19..22] = Wmu,bmu,Wlv,blv : unused (z is dead code)
  const float* Wm1 = (const float*)d_in[23], *bm1 = (const float*)d_in[24];
  const float* Wm2 = (const float*)d_in[25], *bm2 = (const float*)d_in[26];
  const float* Wcls= (const float*)d_in[27], *bcls= (const float*)d_in[28];
  float* out = (float*)d_out;

  const int N = in_sizes[0] / 512;
  const int E = in_sizes[5];

  float* ws = (float*)d_ws;
  size_t off = 0;
  float* nf     = ws + off;  off += (size_t)N * 64;
  float* Atab   = ws + off;  off += (size_t)N * 3 * 64;
  float* Btab   = ws + off;  off += (size_t)N * 3 * 64;
  int*   head   = (int*)(ws + off);  off += (size_t)N;
  int*   nxt    = (int*)(ws + off);  off += (size_t)E;
  short* Wfhi   = (short*)(ws + off);  off += (1728 * 64) / 2;
  short* Wflo   = (short*)(ws + off);  off += (1728 * 64) / 2;

  init_head<<<(N + 255) / 256, 256, 0, stream>>>(head, N);

  prep_w<<<(1728 * 64 + 255) / 256, 256, 0, stream>>>(Wi, Wt, Wn, Wc, Wf, Wm1,
                                                      Wfhi, Wflo);

  const int gN = (N + 63) / 64;
  encoder<<<gN, 256, 0, stream>>>(image, tweets, num_prop, category,
                                  Wfhi, Wflo, bi, bt, bn, bc, bf, nf, N);

  const int N3 = N * 3;
  const int gT = (N3 + 63) / 64;
  table_kernel<<<2 * gT, 256, 0, stream>>>(nf, Eet, Wfhi, Wflo, bm1,
                                           Atab, Btab, N3, gT);

  edge_kernel<<<(E + 15) / 16, 256, 0, stream>>>(ei, et, u, Atab, Btab,
                                                 Wm2, bm2, head, nxt, E);

  node_kernel<<<(N + 3) / 4, 256, 0, stream>>>(head, nxt, ei, nf, Wcls, bcls,
                                               out, N, E);
}

// Round 7
// 329.827 us; speedup vs baseline: 1.3431x; 1.3431x over previous
//
#include <hip/hip_runtime.h>
#include <cstdint>

typedef short short8 __attribute__((ext_vector_type(8)));
typedef float f32x4  __attribute__((ext_vector_type(4)));

// RNE float -> bf16 hi + bf16 lo split (scalar)
__device__ __forceinline__ void split2(float x, short& h, short& l) {
  unsigned u  = __float_as_uint(x);
  unsigned rh = u + 0x7FFFu + ((u >> 16) & 1u);
  h = (short)(rh >> 16);
  float hf = __uint_as_float((rh >> 16) << 16);
  float lf = x - hf;
  unsigned ul = __float_as_uint(lf);
  unsigned rl = ul + 0x7FFFu + ((ul >> 16) & 1u);
  l = (short)(rl >> 16);
}

// float4 -> packed bf16 hi pair + lo pair (v_cvt_pk_bf16_f32)
__device__ __forceinline__ void split4(float4 a, uint2& hp, uint2& lp) {
  unsigned hp0, hp1, lp0, lp1;
  asm("v_cvt_pk_bf16_f32 %0, %1, %2" : "=v"(hp0) : "v"(a.x), "v"(a.y));
  asm("v_cvt_pk_bf16_f32 %0, %1, %2" : "=v"(hp1) : "v"(a.z), "v"(a.w));
  float h0 = __uint_as_float(hp0 << 16);
  float h1 = __uint_as_float(hp0 & 0xFFFF0000u);
  float h2 = __uint_as_float(hp1 << 16);
  float h3 = __uint_as_float(hp1 & 0xFFFF0000u);
  float l0 = a.x - h0, l1 = a.y - h1, l2 = a.z - h2, l3 = a.w - h3;
  asm("v_cvt_pk_bf16_f32 %0, %1, %2" : "=v"(lp0) : "v"(l0), "v"(l1));
  asm("v_cvt_pk_bf16_f32 %0, %1, %2" : "=v"(lp1) : "v"(l2), "v"(l3));
  hp = make_uint2(hp0, hp1);
  lp = make_uint2(lp0, lp1);
}

// ---------------------------------------------------------------------------
__global__ __launch_bounds__(256) void init_head(int* __restrict__ head, int N)
{
  const int i = blockIdx.x * 256 + threadIdx.x;
  if (i < N) head[i] = -1;
}

// ---------------------------------------------------------------------------
// Pre-convert all weight matrices [K][64] f32 -> bf16 hi/lo in MFMA B-frag
// order. k-row segments (padded to mult of 32):
//   Wi:0(512) Wt:512(768) Wn:1280(K=16) Wc:1312(K=8) Wf:1344(256)
//   Wm1A:1600(64) Wm1B:1664(64)   total 1728 k-rows -> steps 0..53
// ---------------------------------------------------------------------------
__global__ __launch_bounds__(256) void prep_w(
    const float* __restrict__ Wi, const float* __restrict__ Wt,
    const float* __restrict__ Wn, const float* __restrict__ Wc,
    const float* __restrict__ Wf, const float* __restrict__ Wm1,
    short* __restrict__ hi, short* __restrict__ lo)
{
  int idx = blockIdx.x * 256 + threadIdx.x;
  if (idx >= 1728 * 64) return;
  int kp = idx >> 6, col = idx & 63;
  const float* W; int K, kloc, base;
  if (kp < 512)       { W = Wi;            K = 512; kloc = kp;        base = 0;    }
  else if (kp < 1280) { W = Wt;            K = 768; kloc = kp - 512;  base = 512;  }
  else if (kp < 1312) { W = Wn;            K = 16;  kloc = kp - 1280; base = 1280; }
  else if (kp < 1344) { W = Wc;            K = 8;   kloc = kp - 1312; base = 1312; }
  else if (kp < 1600) { W = Wf;            K = 256; kloc = kp - 1344; base = 1344; }
  else if (kp < 1664) { W = Wm1;           K = 64;  kloc = kp - 1600; base = 1600; }
  else                { W = Wm1 + 64 * 64; K = 64;  kloc = kp - 1664; base = 1664; }
  float x = (kloc < K) ? W[(size_t)kloc * 64 + col] : 0.f;
  short h, l; split2(x, h, l);
  int s = kloc >> 5;
  int addr = ((s * 4 + (col >> 4)) * 64 + ((col & 15) | (((kloc >> 3) & 3) << 4))) * 8 + (kloc & 7);
  size_t o = (size_t)base * 64 + addr;
  hi[o] = h; lo[o] = l;
}

// ---------------------------------------------------------------------------
// Fused encoder v3: NO LDS / NO barriers in the K-loop.
// Each wave owns 16 output rows; its A-fragment for 16x16x32 MFMA is
// lane l <- A[row=l&15][k=(l>>4)*8 + j], loaded DIRECTLY from global as two
// float4 (wave coalesces to 16 x 128B rows), split to bf16 hi/lo in regs.
// W read direct from L2 (prepped frag order). Stage-2 uses a per-wave
// 16x68 LDS patch for the D->A transpose (lgkmcnt only, no syncthreads).
// ---------------------------------------------------------------------------
__global__ __launch_bounds__(256) void encoder(
    const float* __restrict__ image, const float* __restrict__ tweets,
    const float* __restrict__ nump, const float* __restrict__ catg,
    const short* __restrict__ Whi, const short* __restrict__ Wlo,
    const float* __restrict__ bi, const float* __restrict__ bt,
    const float* __restrict__ bn, const float* __restrict__ bc,
    const float* __restrict__ bf, float* __restrict__ nf, int M)
{
  __shared__ float hbuf[4][16 * 68 + 4];
  const int tid = threadIdx.x;
  const int m0  = blockIdx.x * 64;
  const int w   = tid >> 6, l = tid & 63;
  const int r   = l & 15;          // fragment row (within wave's 16 rows)
  const int g   = l >> 4;          // k-group: k = g*8 + j
  int grow = m0 + w * 16 + r;      // global row for A loads
  if (grow >= M) grow = M - 1;     // clamp; results of dup rows never stored

  f32x4 acc[4], acc2[4];
#pragma unroll
  for (int n = 0; n < 4; n++) {
    acc[n]  = (f32x4){0.f, 0.f, 0.f, 0.f};
    acc2[n] = (f32x4){0.f, 0.f, 0.f, 0.f};
  }

  // one K-step (32 wide) of stage-1: a0 = k[g*8..+3], a1 = k[g*8+4..+7]
  auto mfma_step = [&](float4 a0, float4 a1, int wstep, f32x4* ac) {
    uint2 h01, l01, h23, l23;
    split4(a0, h01, l01);
    split4(a1, h23, l23);
    uint4 ahi_u = make_uint4(h01.x, h01.y, h23.x, h23.y);
    uint4 alo_u = make_uint4(l01.x, l01.y, l23.x, l23.y);
    short8 ahi = *reinterpret_cast<short8*>(&ahi_u);
    short8 alo = *reinterpret_cast<short8*>(&alo_u);
#pragma unroll
    for (int n = 0; n < 4; n++) {
      short8 whi = *reinterpret_cast<const short8*>(&Whi[((size_t)(wstep * 4 + n)) * 512 + l * 8]);
      short8 wlo = *reinterpret_cast<const short8*>(&Wlo[((size_t)(wstep * 4 + n)) * 512 + l * 8]);
      ac[n] = __builtin_amdgcn_mfma_f32_16x16x32_bf16(ahi, whi, ac[n], 0, 0, 0);
      ac[n] = __builtin_amdgcn_mfma_f32_16x16x32_bf16(alo, whi, ac[n], 0, 0, 0);
      ac[n] = __builtin_amdgcn_mfma_f32_16x16x32_bf16(ahi, wlo, ac[n], 0, 0, 0);
    }
  };

  // stage-2: per-wave D->A transpose through private LDS patch, then MFMA
  // into acc2 against Wf k-block of this segment. No cross-wave sync needed.
  auto seg2_phase = [&](int seg, const float* __restrict__ bias) {
    float* hb = hbuf[w];
#pragma unroll
    for (int n = 0; n < 4; n++) {
      const int c  = n * 16 + r;
      const float bb = bias[c];
#pragma unroll
      for (int j = 0; j < 4; j++) {
        const int row = g * 4 + j;              // D layout: row=(l>>4)*4+j
        hb[row * 68 + c] = fmaxf(acc[n][j] + bb, 0.f);
      }
      acc[n] = (f32x4){0.f, 0.f, 0.f, 0.f};
    }
    asm volatile("s_waitcnt lgkmcnt(0)" ::: "memory");
    __builtin_amdgcn_sched_barrier(0);
#pragma unroll
    for (int ks2 = 0; ks2 < 2; ks2++) {
      float4 b0 = *reinterpret_cast<const float4*>(&hb[r * 68 + ks2 * 32 + g * 8]);
      float4 b1 = *reinterpret_cast<const float4*>(&hb[r * 68 + ks2 * 32 + g * 8 + 4]);
      mfma_step(b0, b1, 42 + seg * 2 + ks2, acc2);
    }
    // reads are consumed (split4) before any later LDS write can issue, so
    // the next segment's writes to hb cannot overtake them.
  };

  // ---- stage 1, segment 0: image (K=512, 16 steps) ----
#pragma unroll 4
  for (int t = 0; t < 16; t++) {
    const float* ap = image + (size_t)grow * 512 + t * 32 + g * 8;
    float4 a0 = *reinterpret_cast<const float4*>(ap);
    float4 a1 = *reinterpret_cast<const float4*>(ap + 4);
    mfma_step(a0, a1, t, acc);
  }
  seg2_phase(0, bi);

  // ---- segment 1: tweets (K=768, 24 steps) ----
#pragma unroll 4
  for (int t = 0; t < 24; t++) {
    const float* ap = tweets + (size_t)grow * 768 + t * 32 + g * 8;
    float4 a0 = *reinterpret_cast<const float4*>(ap);
    float4 a1 = *reinterpret_cast<const float4*>(ap + 4);
    mfma_step(a0, a1, 16 + t, acc);
  }
  seg2_phase(1, bt);

  // ---- segment 2: num_prop (K=16: only g<2 lanes have valid k) ----
  {
    float4 a0 = make_float4(0.f, 0.f, 0.f, 0.f);
    float4 a1 = make_float4(0.f, 0.f, 0.f, 0.f);
    if (g < 2) {
      const float* ap = nump + (size_t)grow * 16 + g * 8;
      a0 = *reinterpret_cast<const float4*>(ap);
      a1 = *reinterpret_cast<const float4*>(ap + 4);
    }
    mfma_step(a0, a1, 40, acc);
  }
  seg2_phase(2, bn);

  // ---- segment 3: category (K=8: only g==0 lanes valid) ----
  {
    float4 a0 = make_float4(0.f, 0.f, 0.f, 0.f);
    float4 a1 = make_float4(0.f, 0.f, 0.f, 0.f);
    if (g == 0) {
      const float* ap = catg + (size_t)grow * 8;
      a0 = *reinterpret_cast<const float4*>(ap);
      a1 = *reinterpret_cast<const float4*>(ap + 4);
    }
    mfma_step(a0, a1, 41, acc);
  }
  seg2_phase(3, bc);

  // ---- epilogue: nf = relu(acc2 + bf) ----
  const int rb  = m0 + w * 16 + g * 4;
#pragma unroll
  for (int n = 0; n < 4; n++) {
    const int c = n * 16 + r;
    const float bb = bf[c];
#pragma unroll
    for (int j = 0; j < 4; j++) {
      const int rr = rb + j;
      if (rr < M) nf[(size_t)rr * 64 + c] = fmaxf(acc2[n][j] + bb, 0.f);
    }
  }
}

// ---------------------------------------------------------------------------
// Edge tables via MFMA. blocks [0,gT): Atab   blocks [gT,2gT): Btab
// ---------------------------------------------------------------------------
__global__ __launch_bounds__(256) void table_kernel(
    const float* __restrict__ nf, const float* __restrict__ Eet,
    const short* __restrict__ Whi, const short* __restrict__ Wlo,
    const float* __restrict__ bm1,
    float* __restrict__ Atab, float* __restrict__ Btab, int N3, int gT)
{
  const bool isB    = (int)blockIdx.x >= gT;
  const int  m0     = (isB ? (int)blockIdx.x - gT : (int)blockIdx.x) * 64;
  const int  eoff   = isB ? 64 : 0;
  const int  wstep0 = isB ? 52 : 50;
  float*     Tab    = isB ? Btab : Atab;

  __shared__ short Ahi[2][2048];
  __shared__ short Alo[2][2048];
  const int tid  = threadIdx.x;
  const int w    = tid >> 6, l = tid & 63;
  const int srow = tid >> 3;
  const int k0   = (tid & 7) * 4;
  const int i0   = k0 & 7;
  const int kg   = k0 >> 3;

#pragma unroll
  for (int ks2 = 0; ks2 < 2; ks2++) {
#pragma unroll
    for (int r2 = 0; r2 < 2; r2++) {
      const int row = srow + r2 * 32;
      const int rg  = m0 + row;
      float4 v = make_float4(0.f, 0.f, 0.f, 0.f);
      if (rg < N3) {
        const int n = rg / 3;
        const int t = rg - n * 3;
        const int k = ks2 * 32 + k0;
        float4 x = *reinterpret_cast<const float4*>(&nf[(size_t)n * 64 + k]);
        float4 e = *reinterpret_cast<const float4*>(&Eet[(size_t)t * 128 + eoff + k]);
        v.x = fmaxf(x.x + e.x, 0.f); v.y = fmaxf(x.y + e.y, 0.f);
        v.z = fmaxf(x.z + e.z, 0.f); v.w = fmaxf(x.w + e.w, 0.f);
      }
      uint2 hp, lp; split4(v, hp, lp);
      const int addr = (row >> 4) * 512 + (((row & 15) | (kg << 4)) * 8 + i0);
      *reinterpret_cast<uint2*>(&Ahi[ks2][addr]) = hp;
      *reinterpret_cast<uint2*>(&Alo[ks2][addr]) = lp;
    }
  }
  __syncthreads();

  f32x4 acc[4];
#pragma unroll
  for (int n = 0; n < 4; n++) acc[n] = (f32x4){0.f, 0.f, 0.f, 0.f};

#pragma unroll
  for (int ks2 = 0; ks2 < 2; ks2++) {
    short8 ahi = *reinterpret_cast<const short8*>(&Ahi[ks2][w * 512 + l * 8]);
    short8 alo = *reinterpret_cast<const short8*>(&Alo[ks2][w * 512 + l * 8]);
#pragma unroll
    for (int n = 0; n < 4; n++) {
      short8 whi = *reinterpret_cast<const short8*>(&Whi[((size_t)(wstep0 + ks2) * 4 + n) * 512 + l * 8]);
      short8 wlo = *reinterpret_cast<const short8*>(&Wlo[((size_t)(wstep0 + ks2) * 4 + n) * 512 + l * 8]);
      acc[n] = __builtin_amdgcn_mfma_f32_16x16x32_bf16(ahi, whi, acc[n], 0, 0, 0);
      acc[n] = __builtin_amdgcn_mfma_f32_16x16x32_bf16(alo, whi, acc[n], 0, 0, 0);
      acc[n] = __builtin_amdgcn_mfma_f32_16x16x32_bf16(ahi, wlo, acc[n], 0, 0, 0);
    }
  }

  const int rb  = m0 + w * 16 + (l >> 4) * 4;
  const int c15 = l & 15;
#pragma unroll
  for (int n = 0; n < 4; n++) {
    const int c = n * 16 + c15;
    const float bb = isB ? 0.f : bm1[c];
#pragma unroll
    for (int j = 0; j < 4; j++) {
      const int rr = rb + j;
      if (rr < N3) Tab[(size_t)rr * 64 + c] = acc[n][j] + bb;
    }
  }
}

// ---------------------------------------------------------------------------
// 16 lanes per edge: logits -> sigmoid -> Bernoulli(u) -> linked list append
// ---------------------------------------------------------------------------
__global__ __launch_bounds__(256) void edge_kernel(
    const int* __restrict__ ei, const int* __restrict__ et,
    const float* __restrict__ u,
    const float* __restrict__ Atab, const float* __restrict__ Btab,
    const float* __restrict__ Wm2, const float* __restrict__ bm2,
    int* __restrict__ head, int* __restrict__ nxt, int E)
{
  const int tid = threadIdx.x;
  const int e   = blockIdx.x * 16 + (tid >> 4);
  const int sub = tid & 15;
  if (e >= E) return;

  const int sn = ei[e];
  const int dn = ei[E + e];
  const int t  = et[e];

  float4 a  = *reinterpret_cast<const float4*>(Atab + ((size_t)sn * 3 + t) * 64 + sub * 4);
  float4 b  = *reinterpret_cast<const float4*>(Btab + ((size_t)dn * 3 + t) * 64 + sub * 4);
  float4 wv = *reinterpret_cast<const float4*>(Wm2 + sub * 4);

  float v = fmaxf(a.x + b.x, 0.f) * wv.x;
  v = fmaf(fmaxf(a.y + b.y, 0.f), wv.y, v);
  v = fmaf(fmaxf(a.z + b.z, 0.f), wv.z, v);
  v = fmaf(fmaxf(a.w + b.w, 0.f), wv.w, v);
  v += __shfl_xor(v, 1);
  v += __shfl_xor(v, 2);
  v += __shfl_xor(v, 4);
  v += __shfl_xor(v, 8);

  if (sub == 0) {
    const float p = 1.f / (1.f + expf(-(v + bm2[0])));
    if (u[e] < p) {
      nxt[e] = atomicExch(&head[sn], e);
    }
  }
}

// ---------------------------------------------------------------------------
// one wave per node: walk chain, accumulate nf[dst] in double, out = agg@Wcls
// ---------------------------------------------------------------------------
__global__ __launch_bounds__(256) void node_kernel(
    const int* __restrict__ head, const int* __restrict__ nxt,
    const int* __restrict__ ei,
    const float* __restrict__ nf,
    const float* __restrict__ Wcls, const float* __restrict__ bcls,
    float* __restrict__ out, int N, int E)
{
  const int n    = (int)((blockIdx.x * (unsigned)blockDim.x + threadIdx.x) >> 6);
  const int lane = threadIdx.x & 63;
  if (n >= N) return;

  double acc = 0.0;
  int    c   = 0;
  int    e   = head[n];
  while (e >= 0) {
    const int dn = ei[E + e];
    acc += (double)nf[(size_t)dn * 64 + lane];
    c++;
    e = nxt[e];
  }

  const float agg = (c > 0) ? (float)(acc / (double)c) : nf[(size_t)n * 64 + lane];
  float r0 = agg * Wcls[lane * 2 + 0];
  float r1 = agg * Wcls[lane * 2 + 1];
#pragma unroll
  for (int off = 32; off; off >>= 1) {
    r0 += __shfl_xor(r0, off, 64);
    r1 += __shfl_xor(r1, off, 64);
  }
  if (lane == 0) {
    out[(size_t)n * 2 + 0] = r0 + bcls[0];
    out[(size_t)n * 2 + 1] = r1 + bcls[1];
  }
}

// ---------------------------------------------------------------------------
extern "C" void kernel_launch(void* const* d_in, const int* in_sizes, int n_in,
                              void* d_out, int out_size, void* d_ws, size_t ws_size,
                              hipStream_t stream)
{
  const float* image    = (const float*)d_in[0];
  const float* tweets   = (const float*)d_in[1];
  const float* num_prop = (const float*)d_in[2];
  const float* category = (const float*)d_in[3];
  const int*   ei       = (const int*)  d_in[4];
  const int*   et       = (const int*)  d_in[5];
  // d_in[6] = eps : unused (z is dead code)
  const float* u        = (const float*)d_in[7];
  const float* Wi  = (const float*)d_in[8],  *bi  = (const float*)d_in[9];
  const float* Wt  = (const float*)d_in[10], *bt  = (const float*)d_in[11];
  const float* Wn  = (const float*)d_in[12], *bn  = (const float*)d_in[13];
  const float* Wc  = (const float*)d_in[14], *bc  = (const float*)d_in[15];
  const float* Wf  = (const float*)d_in[16], *bf  = (const float*)d_in[17];
  const float* Eet = (const float*)d_in[18];
  // d_in[19..22] = Wmu,bmu,Wlv,blv : unused (z is dead code)
  const float* Wm1 = (const float*)d_in[23], *bm1 = (const float*)d_in[24];
  const float* Wm2 = (const float*)d_in[25], *bm2 = (const float*)d_in[26];
  const float* Wcls= (const float*)d_in[27], *bcls= (const float*)d_in[28];
  float* out = (float*)d_out;

  const int N = in_sizes[0] / 512;
  const int E = in_sizes[5];

  float* ws = (float*)d_ws;
  size_t off = 0;
  float* nf     = ws + off;  off += (size_t)N * 64;
  float* Atab   = ws + off;  off += (size_t)N * 3 * 64;
  float* Btab   = ws + off;  off += (size_t)N * 3 * 64;
  int*   head   = (int*)(ws + off);  off += (size_t)N;
  int*   nxt    = (int*)(ws + off);  off += (size_t)E;
  short* Wfhi   = (short*)(ws + off);  off += (1728 * 64) / 2;
  short* Wflo   = (short*)(ws + off);  off += (1728 * 64) / 2;

  init_head<<<(N + 255) / 256, 256, 0, stream>>>(head, N);

  prep_w<<<(1728 * 64 + 255) / 256, 256, 0, stream>>>(Wi, Wt, Wn, Wc, Wf, Wm1,
                                                      Wfhi, Wflo);

  const int gN = (N + 63) / 64;
  encoder<<<gN, 256, 0, stream>>>(image, tweets, num_prop, category,
                                  Wfhi, Wflo, bi, bt, bn, bc, bf, nf, N);

  const int N3 = N * 3;
  const int gT = (N3 + 63) / 64;
  table_kernel<<<2 * gT, 256, 0, stream>>>(nf, Eet, Wfhi, Wflo, bm1,
                                           Atab, Btab, N3, gT);

  edge_kernel<<<(E + 15) / 16, 256, 0, stream>>>(ei, et, u, Atab, Btab,
                                                 Wm2, bm2, head, nxt, E);

  node_kernel<<<(N + 3) / 4, 256, 0, stream>>>(head, nxt, ei, nf, Wcls, bcls,
                                               out, N, E);
}